// Round 6
// baseline (151.860 us; speedup 1.0000x reference)
//
#include <hip/hip_runtime.h>
#include <hip/hip_bf16.h>

// Problem constants (B,H,W,C) = (4,56,56,256), nh=8, K=7, lr=4, hd=32
#define BD 4
#define HD_ 56
#define WD 56
#define CD 256
#define NH 8
#define KW 7
#define LR 4
#define HDIM 32
#define MB (HD_*WD)              // 3136 rows per batch
#define NROWS (BD*MB)            // 12544 total rows
#define QK_PER_B (HD_*WD*32)     // 100352  (q/k per-batch elements)
#define V_PER_B  (HD_*WD*256)    // 802816

typedef short short8 __attribute__((ext_vector_type(8)));   // 8 bf16 (4 VGPRs)
typedef float floatx4 __attribute__((ext_vector_type(4)));  // MFMA C/D

static __device__ inline ushort f2bf(float f) {
    __hip_bfloat16 h = __float2bfloat16(f);
    return *(ushort*)&h;
}
static __device__ inline float bf2f(uint h16) {          // h16 = bf16 in low 16 bits
    union { uint u; float f; } c; c.u = h16 << 16; return c.f;
}
static __device__ inline float bf2f_hi(uint u) {         // bf16 in high 16 bits
    union { uint v; float f; } c; c.v = u & 0xffff0000u; return c.f;
}

// global -> LDS async DMA, 16B per lane. LDS dest is wave-uniform base +
// lane*16 (HW behavior); global src is per-lane.
typedef const __attribute__((address_space(1))) void* gp1_t;
typedef __attribute__((address_space(3))) void* sp3_t;
static __device__ __forceinline__ void glds16(const void* g, void* s) {
    __builtin_amdgcn_global_load_lds((gp1_t)g, (sp3_t)s, 16, 0, 0);
}

// ---------------- prep: x->bf16 + transposed bf16 weights + packed bias -----
__global__ __launch_bounds__(256) void prep_all(
    const float* __restrict__ x,
    const float* __restrict__ Wq, const float* __restrict__ Wk,
    const float* __restrict__ Wv, const float* __restrict__ bq,
    const float* __restrict__ bk, const float* __restrict__ bv,
    const float* __restrict__ Wp,
    ushort* __restrict__ xb, ushort* __restrict__ WpkT,
    ushort* __restrict__ WpT, float* __restrict__ pb)
{
    int idx = blockIdx.x * 256 + threadIdx.x;
    if (idx < 401408) {
        float4 f0 = *(const float4*)&x[idx * 8];
        float4 f1 = *(const float4*)&x[idx * 8 + 4];
        union { ushort h[8]; uint4 u; } p;
        p.h[0] = f2bf(f0.x); p.h[1] = f2bf(f0.y); p.h[2] = f2bf(f0.z); p.h[3] = f2bf(f0.w);
        p.h[4] = f2bf(f1.x); p.h[5] = f2bf(f1.y); p.h[6] = f2bf(f1.z); p.h[7] = f2bf(f1.w);
        *(uint4*)&xb[idx * 8] = p.u;
    } else if (idx < 401408 + 81920) {
        int j = idx - 401408;
        int n = j >> 8, k = j & 255;
        float v;
        if (n < 32)       v = Wq[k * 32 + n];
        else if (n < 64)  v = Wk[k * 32 + (n - 32)];
        else              v = Wv[k * 256 + (n - 64)];
        WpkT[j] = f2bf(v);
    } else if (idx < 401408 + 81920 + 65536) {
        int j = idx - (401408 + 81920);
        int n = j >> 8, k = j & 255;
        WpT[j] = f2bf(Wp[k * 256 + n]);
    } else if (idx < 401408 + 81920 + 65536 + 320) {
        int n = idx - (401408 + 81920 + 65536);
        pb[n] = (n < 32) ? bq[n] : (n < 64) ? bk[n - 32] : bv[n - 64];
    }
}

// ---------------- MFMA GEMM: QKV projection (proven) ------------------------
static __device__ __forceinline__ void gemm_core_128x64(
    const ushort* __restrict__ Ag, const ushort* __restrict__ Bg,
    ushort* As, ushort* Bs, int m0, int n0, int t, floatx4 (&acc)[4][2])
{
    const int lane = t & 63, w = t >> 6;
    const int lx = lane & 7, ly = lane >> 3;
    const int koff = (lx ^ ly) << 3;
    const int col = lane & 15, quad = lane >> 4;
    const int swz = (col & 7) << 4;
    const int wm = w >> 1, wn = w & 1;
    char* Ac = (char*)As;
    char* Bc = (char*)Bs;

    for (int k0 = 0; k0 < 256; k0 += 64) {
        __syncthreads();
#pragma unroll
        for (int l = 0; l < 4; ++l) {
            int c = (w << 2) + l;
            int row = (c << 3) + ly;
            glds16(&Ag[(m0 + row) * 256 + k0 + koff], &As[c << 9]);
        }
#pragma unroll
        for (int l = 0; l < 2; ++l) {
            int c = (w << 1) + l;
            int row = (c << 3) + ly;
            glds16(&Bg[(n0 + row) * 256 + k0 + koff], &Bs[c << 9]);
        }
        __syncthreads();
#pragma unroll
        for (int kk = 0; kk < 2; ++kk) {
            const int kx = ((kk << 6) + (quad << 4)) ^ swz;
            short8 b0 = *(short8*)(Bc + ((wn << 5) + col) * 128 + kx);
            short8 b1 = *(short8*)(Bc + ((wn << 5) + 16 + col) * 128 + kx);
#pragma unroll
            for (int mt = 0; mt < 4; ++mt) {
                short8 a = *(short8*)(Ac + ((wm << 6) + (mt << 4) + col) * 128 + kx);
                acc[mt][0] = __builtin_amdgcn_mfma_f32_16x16x32_bf16(a, b0, acc[mt][0], 0, 0, 0);
                acc[mt][1] = __builtin_amdgcn_mfma_f32_16x16x32_bf16(a, b1, acc[mt][1], 0, 0, 0);
            }
        }
    }
}

__global__ __launch_bounds__(256) void mfma_qkv(
    const ushort* __restrict__ xb, const ushort* __restrict__ Bt,
    const float* __restrict__ pb, ushort* __restrict__ Qb,
    ushort* __restrict__ Kb, ushort* __restrict__ Vb)
{
    __shared__ ushort As[128 * 64];
    __shared__ ushort Bs[64 * 64];
    const int t = threadIdx.x;
    const int m0 = blockIdx.y * 128, n0 = blockIdx.x * 64;

    floatx4 acc[4][2] = {};
    gemm_core_128x64(xb, Bt, As, Bs, m0, n0, t, acc);

    const int lane = t & 63, w = t >> 6;
    const int col = lane & 15, quad = lane >> 4;
    const int wm = w >> 1, wn = w & 1;
#pragma unroll
    for (int mt = 0; mt < 4; ++mt) {
#pragma unroll
        for (int nt = 0; nt < 2; ++nt) {
            int gn = n0 + (wn << 5) + (nt << 4) + col;
            float bias = pb[gn];
#pragma unroll
            for (int rg = 0; rg < 4; ++rg) {
                int m = m0 + (wm << 6) + (mt << 4) + (quad << 2) + rg;
                ushort h = f2bf(acc[mt][nt][rg] + bias);
                if (gn < 32)        Qb[m * 32 + gn] = h;
                else if (gn < 64)   Kb[m * 32 + (gn - 32)] = h;
                else                Vb[m * 256 + (gn - 64)] = h;
            }
        }
    }
}

// ---------------- NATTEN attention v4 (unchanged from round 5) --------------
__global__ __launch_bounds__(256, 6) void natten_attn4(
    const ushort* __restrict__ Qb, const ushort* __restrict__ Kb,
    const ushort* __restrict__ Vb, const float* __restrict__ rpb,
    ushort* __restrict__ Ab)
{
    __shared__ __align__(16) ushort Pl[32 * 168];   // 10752 B  P[q][key]
    __shared__ __align__(16) ushort Vt[32 * 168];   // 10752 B  V^T[ch][key]
    __shared__ float4 Ksf[140];                     // 2240 B
    __shared__ float  Rs[169];                      // 676 B
    __shared__ float  invS[32];                     // 128 B

    const int tj = blockIdx.x, ti = blockIdx.y;
    const int h = blockIdx.z & 7, b = blockIdx.z >> 3;
    const int t = threadIdx.x;
    const int i0 = ti * 4, j0 = tj * 8;
    const int rs = min(max(i0 - 3, 0), HD_ - 10);
    const int cs = min(max(j0 - 3, 0), WD - 14);

    const ushort* kb = Kb + (size_t)b * QK_PER_B + h * (HD_ * WD * LR);
    const ushort* vb = Vb + (size_t)b * V_PER_B + h * (HD_ * WD * HDIM);

#pragma unroll
    for (int it = 0; it < 3; ++it) {
        int idx = t + (it << 8);
        if (idx < 672) {
            *(uint4*)&Pl[idx << 3] = make_uint4(0, 0, 0, 0);
            *(uint4*)&Vt[idx << 3] = make_uint4(0, 0, 0, 0);
        }
    }
    __syncthreads();

    if (t < 140) {
        int r = t / 14, c = t % 14;
        uint2 kr = *(const uint2*)&kb[(rs + r) * (WD * LR) + (cs + c) * LR];
        Ksf[t] = make_float4(bf2f(kr.x & 0xffff), bf2f_hi(kr.x),
                             bf2f(kr.y & 0xffff), bf2f_hi(kr.y));
    }
    if (t < 169) Rs[t] = rpb[h * 169 + t];
#pragma unroll
    for (int it = 0; it < 3; ++it) {
        int idx = t + (it << 8);
        if (idx < 560) {
            int oct = idx / 140, pos = idx % 140;
            int r = pos / 14, c = pos % 14;
            union { uint4 u; ushort hh[8]; } vv;
            vv.u = *(const uint4*)&vb[(rs + r) * (WD * HDIM) + (cs + c) * HDIM + oct * 8];
            ushort* cp = &Vt[(oct * 8) * 168 + pos];
#pragma unroll
            for (int e = 0; e < 8; ++e) cp[e * 168] = vv.hh[e];
        }
    }

    const int q  = t >> 3, p = t & 7;
    const int qi = q >> 3, qj = q & 7;
    const int i = i0 + qi, j = j0 + qj;
    uint2 qr2 = *(const uint2*)&Qb[(size_t)b * QK_PER_B + h * (HD_ * WD * LR) + i * (WD * LR) + j * LR];
    __syncthreads();

    const int sh = min(max(i - 3, 0), HD_ - KW);
    const int sw = min(max(j - 3, 0), WD - KW);
    const int oh = sh - rs, ow = sw - cs;
    const int rb0 = (sh - i + 6) * 13 + (sw - j + 6);
    const float scale = 0.17677669529663687f;
    float qx = bf2f(qr2.x & 0xffff) * scale, qy = bf2f_hi(qr2.x) * scale;
    float qz = bf2f(qr2.y & 0xffff) * scale, qw = bf2f_hi(qr2.y) * scale;

    float sum = 0.f;
    if (p < 7) {
        int kpos  = (oh + p) * 14 + ow;
        int rbase = rb0 + p * 13;
        ushort* prow = &Pl[q * 168 + kpos];
#pragma unroll
        for (int kw = 0; kw < 7; ++kw) {
            float4 kf = Ksf[kpos + kw];
            float d = Rs[rbase + kw];
            d = fmaf(qx, kf.x, d);
            d = fmaf(qy, kf.y, d);
            d = fmaf(qz, kf.z, d);
            d = fmaf(qw, kf.w, d);
            float e = __expf(d);
            sum += e;
            prow[kw] = f2bf(e);
        }
    }
    sum += __shfl_xor(sum, 1);
    sum += __shfl_xor(sum, 2);
    sum += __shfl_xor(sum, 4);
    if (p == 0) invS[q] = 1.0f / sum;
    __syncthreads();

    const int lane = t & 63, w = t >> 6;
    const int col = lane & 15, quad = lane >> 4;
    const int wm = w & 1, wn = w >> 1;
    floatx4 acc = {0.f, 0.f, 0.f, 0.f};
    const ushort* arow = &Pl[(wm * 16 + col) * 168];
    const ushort* brow = &Vt[(wn * 16 + col) * 168];
#pragma unroll
    for (int s = 0; s < 5; ++s) {
        int ko = s * 32 + quad * 8;
        short8 a  = *(const short8*)(arow + ko);
        short8 bb = *(const short8*)(brow + ko);
        acc = __builtin_amdgcn_mfma_f32_16x16x32_bf16(a, bb, acc, 0, 0, 0);
    }

#pragma unroll
    for (int rg = 0; rg < 4; ++rg) {
        int qq = wm * 16 + quad * 4 + rg;
        float iv = invS[qq];
        int ii = i0 + (qq >> 3), jj = j0 + (qq & 7);
        Ab[(((b * HD_ + ii) * WD + jj)) * CD + h * HDIM + wn * 16 + col] = f2bf(acc[rg] * iv);
    }
}

// ---------------- MFMA GEMM: output projection, 64x64 tiles -----------------
__global__ __launch_bounds__(256) void mfma_out64(
    const ushort* __restrict__ Ag, const ushort* __restrict__ Bt,
    const float* __restrict__ bp, float* __restrict__ out)
{
    __shared__ ushort As[64 * 64];   // 8 KB
    __shared__ ushort Bs[64 * 64];   // 8 KB
    const int t = threadIdx.x;
    const int m0 = blockIdx.y * 64, n0 = blockIdx.x * 64;
    const int lane = t & 63, w = t >> 6;
    const int lx = lane & 7, ly = lane >> 3;
    const int koff = (lx ^ ly) << 3;
    const int col = lane & 15, quad = lane >> 4;
    const int swz = (col & 7) << 4;
    const int wm = w >> 1, wn = w & 1;
    char* Ac = (char*)As;
    char* Bc = (char*)Bs;
    floatx4 acc[2][2] = {};

    for (int k0 = 0; k0 < 256; k0 += 64) {
        __syncthreads();
#pragma unroll
        for (int l = 0; l < 2; ++l) {
            int c = (w << 1) + l;
            int row = (c << 3) + ly;
            glds16(&Ag[(m0 + row) * 256 + k0 + koff], &As[c << 9]);
            glds16(&Bt[(n0 + row) * 256 + k0 + koff], &Bs[c << 9]);
        }
        __syncthreads();
#pragma unroll
        for (int kk = 0; kk < 2; ++kk) {
            const int kx = ((kk << 6) + (quad << 4)) ^ swz;
            short8 b0 = *(short8*)(Bc + ((wn << 5) + col) * 128 + kx);
            short8 b1 = *(short8*)(Bc + ((wn << 5) + 16 + col) * 128 + kx);
#pragma unroll
            for (int mt = 0; mt < 2; ++mt) {
                short8 a = *(short8*)(Ac + ((wm << 5) + (mt << 4) + col) * 128 + kx);
                acc[mt][0] = __builtin_amdgcn_mfma_f32_16x16x32_bf16(a, b0, acc[mt][0], 0, 0, 0);
                acc[mt][1] = __builtin_amdgcn_mfma_f32_16x16x32_bf16(a, b1, acc[mt][1], 0, 0, 0);
            }
        }
    }

#pragma unroll
    for (int mt = 0; mt < 2; ++mt) {
#pragma unroll
        for (int nt = 0; nt < 2; ++nt) {
            int gn = n0 + (wn << 5) + (nt << 4) + col;
            float bias = bp[gn];
#pragma unroll
            for (int rg = 0; rg < 4; ++rg) {
                int m = m0 + (wm << 5) + (mt << 4) + (quad << 2) + rg;
                out[m * 256 + gn] = acc[mt][nt][rg] + bias;
            }
        }
    }
}

// host-side: run the full 4-kernel chain with a given pointer set
static void run_chain(const float* x, const float* Wq, const float* bq,
                      const float* Wk, const float* bk, const float* Wv,
                      const float* bv, const float* rpb, const float* Wp,
                      const float* bp, ushort* WpkT, ushort* WpT, ushort* Ab,
                      ushort* Qb, ushort* Kb, ushort* Vb, ushort* xb,
                      float* pb, float* out, hipStream_t stream)
{
    prep_all<<<(549184 + 255) / 256, 256, 0, stream>>>(
        x, Wq, Wk, Wv, bq, bk, bv, Wp, xb, WpkT, WpT, pb);
    mfma_qkv<<<dim3(5, NROWS / 128), 256, 0, stream>>>(xb, WpkT, pb, Qb, Kb, Vb);
    natten_attn4<<<dim3(7, 14, 32), 256, 0, stream>>>(Qb, Kb, Vb, rpb, Ab);
    mfma_out64<<<dim3(4, 196), 256, 0, stream>>>(Ab, WpT, bp, out);
}

extern "C" void kernel_launch(void* const* d_in, const int* in_sizes, int n_in,
                              void* d_out, int out_size, void* d_ws, size_t ws_size,
                              hipStream_t stream) {
    const float* x   = (const float*)d_in[0];
    const float* Wq  = (const float*)d_in[1];
    const float* bq  = (const float*)d_in[2];
    const float* Wk  = (const float*)d_in[3];
    const float* bk  = (const float*)d_in[4];
    const float* Wv  = (const float*)d_in[5];
    const float* bv  = (const float*)d_in[6];
    const float* rpb = (const float*)d_in[7];
    const float* Wp  = (const float*)d_in[8];
    const float* bp  = (const float*)d_in[9];
    float* out = (float*)d_out;

    // real workspace layout (first ~21 MB)
    ushort* WpkT = (ushort*)d_ws;          // 81920
    ushort* WpT  = WpkT + 81920;           // 65536
    ushort* Ab   = WpT + 65536;            // 3211264
    ushort* Qb   = Ab + 3211264;           // 401408
    ushort* Kb   = Qb + BD * QK_PER_B;     // 401408
    ushort* Vb   = Kb + BD * QK_PER_B;     // 3211264
    ushort* xb   = Vb + BD * V_PER_B;      // 3211264
    float*  pb   = (float*)(xb + 3211264); // 320

    // MEASUREMENT ROUND: dummy copy of the full chain into scratch
    // (base at +128 MiB) runs FIRST; delta vs round-5's 112.15 µs = true
    // chain duration C on this node, F = 112.15 - C = harness floor.
    ushort* S      = (ushort*)d_ws + (64u << 20);   // +128 MiB
    ushort* WpkT2  = S;
    ushort* WpT2   = WpkT2 + 81920;
    ushort* Ab2    = WpT2 + 65536;
    ushort* Qb2    = Ab2 + 3211264;
    ushort* Kb2    = Qb2 + BD * QK_PER_B;
    ushort* Vb2    = Kb2 + BD * QK_PER_B;
    ushort* xb2    = Vb2 + BD * V_PER_B;
    float*  pb2    = (float*)(xb2 + 3211264);
    float*  out2   = (float*)(pb2 + 320 + 32);      // 12.8 MB scratch output

    run_chain(x, Wq, bq, Wk, bk, Wv, bv, rpb, Wp, bp,
              WpkT2, WpT2, Ab2, Qb2, Kb2, Vb2, xb2, pb2, out2, stream);

    // real chain (identical, produces the graded output)
    run_chain(x, Wq, bq, Wk, bk, Wv, bv, rpb, Wp, bp,
              WpkT, WpT, Ab, Qb, Kb, Vb, xb, pb, out, stream);
}

// Round 7
// 112.633 us; speedup vs baseline: 1.3483x; 1.3483x over previous
//
#include <hip/hip_runtime.h>
#include <hip/hip_bf16.h>

// Problem constants (B,H,W,C) = (4,56,56,256), nh=8, K=7, lr=4, hd=32
#define BD 4
#define HD_ 56
#define WD 56
#define CD 256
#define NH 8
#define KW 7
#define LR 4
#define HDIM 32
#define MB (HD_*WD)              // 3136 rows per batch
#define NROWS (BD*MB)            // 12544 total rows
#define QK_PER_B (HD_*WD*32)     // 100352  (q/k per-batch elements)
#define V_PER_B  (HD_*WD*256)    // 802816

typedef short short8 __attribute__((ext_vector_type(8)));   // 8 bf16 (4 VGPRs)
typedef float floatx4 __attribute__((ext_vector_type(4)));  // MFMA C/D

static __device__ inline ushort f2bf(float f) {
    __hip_bfloat16 h = __float2bfloat16(f);
    return *(ushort*)&h;
}
static __device__ inline float bf2f(uint h16) {          // h16 = bf16 in low 16 bits
    union { uint u; float f; } c; c.u = h16 << 16; return c.f;
}
static __device__ inline float bf2f_hi(uint u) {         // bf16 in high 16 bits
    union { uint v; float f; } c; c.v = u & 0xffff0000u; return c.f;
}

// global -> LDS async DMA, 16B per lane. LDS dest is wave-uniform base +
// lane*16 (HW behavior); global src is per-lane.
typedef const __attribute__((address_space(1))) void* gp1_t;
typedef __attribute__((address_space(3))) void* sp3_t;
static __device__ __forceinline__ void glds16(const void* g, void* s) {
    __builtin_amdgcn_global_load_lds((gp1_t)g, (sp3_t)s, 16, 0, 0);
}

// ---------------- prep: x->bf16 + transposed bf16 weights + packed bias -----
__global__ __launch_bounds__(256) void prep_all(
    const float* __restrict__ x,
    const float* __restrict__ Wq, const float* __restrict__ Wk,
    const float* __restrict__ Wv, const float* __restrict__ bq,
    const float* __restrict__ bk, const float* __restrict__ bv,
    const float* __restrict__ Wp,
    ushort* __restrict__ xb, ushort* __restrict__ WpkT,
    ushort* __restrict__ WpT, float* __restrict__ pb)
{
    int idx = blockIdx.x * 256 + threadIdx.x;
    if (idx < 401408) {
        float4 f0 = *(const float4*)&x[idx * 8];
        float4 f1 = *(const float4*)&x[idx * 8 + 4];
        union { ushort h[8]; uint4 u; } p;
        p.h[0] = f2bf(f0.x); p.h[1] = f2bf(f0.y); p.h[2] = f2bf(f0.z); p.h[3] = f2bf(f0.w);
        p.h[4] = f2bf(f1.x); p.h[5] = f2bf(f1.y); p.h[6] = f2bf(f1.z); p.h[7] = f2bf(f1.w);
        *(uint4*)&xb[idx * 8] = p.u;
    } else if (idx < 401408 + 81920) {
        int j = idx - 401408;
        int n = j >> 8, k = j & 255;
        float v;
        if (n < 32)       v = Wq[k * 32 + n];
        else if (n < 64)  v = Wk[k * 32 + (n - 32)];
        else              v = Wv[k * 256 + (n - 64)];
        WpkT[j] = f2bf(v);
    } else if (idx < 401408 + 81920 + 65536) {
        int j = idx - (401408 + 81920);
        int n = j >> 8, k = j & 255;
        WpT[j] = f2bf(Wp[k * 256 + n]);
    } else if (idx < 401408 + 81920 + 65536 + 320) {
        int n = idx - (401408 + 81920 + 65536);
        pb[n] = (n < 32) ? bq[n] : (n < 64) ? bk[n - 32] : bv[n - 64];
    }
}

// ---------------- MFMA GEMM: QKV projection (proven) ------------------------
static __device__ __forceinline__ void gemm_core_128x64(
    const ushort* __restrict__ Ag, const ushort* __restrict__ Bg,
    ushort* As, ushort* Bs, int m0, int n0, int t, floatx4 (&acc)[4][2])
{
    const int lane = t & 63, w = t >> 6;
    const int lx = lane & 7, ly = lane >> 3;
    const int koff = (lx ^ ly) << 3;
    const int col = lane & 15, quad = lane >> 4;
    const int swz = (col & 7) << 4;
    const int wm = w >> 1, wn = w & 1;
    char* Ac = (char*)As;
    char* Bc = (char*)Bs;

    for (int k0 = 0; k0 < 256; k0 += 64) {
        __syncthreads();
#pragma unroll
        for (int l = 0; l < 4; ++l) {
            int c = (w << 2) + l;
            int row = (c << 3) + ly;
            glds16(&Ag[(m0 + row) * 256 + k0 + koff], &As[c << 9]);
        }
#pragma unroll
        for (int l = 0; l < 2; ++l) {
            int c = (w << 1) + l;
            int row = (c << 3) + ly;
            glds16(&Bg[(n0 + row) * 256 + k0 + koff], &Bs[c << 9]);
        }
        __syncthreads();
#pragma unroll
        for (int kk = 0; kk < 2; ++kk) {
            const int kx = ((kk << 6) + (quad << 4)) ^ swz;
            short8 b0 = *(short8*)(Bc + ((wn << 5) + col) * 128 + kx);
            short8 b1 = *(short8*)(Bc + ((wn << 5) + 16 + col) * 128 + kx);
#pragma unroll
            for (int mt = 0; mt < 4; ++mt) {
                short8 a = *(short8*)(Ac + ((wm << 6) + (mt << 4) + col) * 128 + kx);
                acc[mt][0] = __builtin_amdgcn_mfma_f32_16x16x32_bf16(a, b0, acc[mt][0], 0, 0, 0);
                acc[mt][1] = __builtin_amdgcn_mfma_f32_16x16x32_bf16(a, b1, acc[mt][1], 0, 0, 0);
            }
        }
    }
}

__global__ __launch_bounds__(256) void mfma_qkv(
    const ushort* __restrict__ xb, const ushort* __restrict__ Bt,
    const float* __restrict__ pb, ushort* __restrict__ Qb,
    ushort* __restrict__ Kb, ushort* __restrict__ Vb)
{
    __shared__ ushort As[128 * 64];
    __shared__ ushort Bs[64 * 64];
    const int t = threadIdx.x;
    const int m0 = blockIdx.y * 128, n0 = blockIdx.x * 64;

    floatx4 acc[4][2] = {};
    gemm_core_128x64(xb, Bt, As, Bs, m0, n0, t, acc);

    const int lane = t & 63, w = t >> 6;
    const int col = lane & 15, quad = lane >> 4;
    const int wm = w >> 1, wn = w & 1;
#pragma unroll
    for (int mt = 0; mt < 4; ++mt) {
#pragma unroll
        for (int nt = 0; nt < 2; ++nt) {
            int gn = n0 + (wn << 5) + (nt << 4) + col;
            float bias = pb[gn];
#pragma unroll
            for (int rg = 0; rg < 4; ++rg) {
                int m = m0 + (wm << 6) + (mt << 4) + (quad << 2) + rg;
                ushort h = f2bf(acc[mt][nt][rg] + bias);
                if (gn < 32)        Qb[m * 32 + gn] = h;
                else if (gn < 64)   Kb[m * 32 + (gn - 32)] = h;
                else                Vb[m * 256 + (gn - 64)] = h;
            }
        }
    }
}

// ---------------- NATTEN attention v5: v4 minus the register-cap footgun ----
// ONLY change vs round 5: __launch_bounds__(256) instead of (256, 6).
// The ",6" forced the allocator to <=84 VGPRs; the same per-thread complexity
// measured 132 VGPRs unconstrained in round 4's fused kernel -> ~50 spill
// slots -> >300 MB scratch traffic across 3136 blocks (the "missing" ~25 us).
// Unconstrained: ~110-130 VGPRs -> 4 waves/EU (16 waves/CU) with zero spill;
// LDS (24.5 KB) would permit 6 blocks but VGPR-bound 4 blocks/CU suffices.
__global__ __launch_bounds__(256) void natten_attn4(
    const ushort* __restrict__ Qb, const ushort* __restrict__ Kb,
    const ushort* __restrict__ Vb, const float* __restrict__ rpb,
    ushort* __restrict__ Ab)
{
    __shared__ __align__(16) ushort Pl[32 * 168];   // 10752 B  P[q][key]
    __shared__ __align__(16) ushort Vt[32 * 168];   // 10752 B  V^T[ch][key]
    __shared__ float4 Ksf[140];                     // 2240 B
    __shared__ float  Rs[169];                      // 676 B
    __shared__ float  invS[32];                     // 128 B

    const int tj = blockIdx.x, ti = blockIdx.y;
    const int h = blockIdx.z & 7, b = blockIdx.z >> 3;
    const int t = threadIdx.x;
    const int i0 = ti * 4, j0 = tj * 8;
    const int rs = min(max(i0 - 3, 0), HD_ - 10);
    const int cs = min(max(j0 - 3, 0), WD - 14);

    const ushort* kb = Kb + (size_t)b * QK_PER_B + h * (HD_ * WD * LR);
    const ushort* vb = Vb + (size_t)b * V_PER_B + h * (HD_ * WD * HDIM);

#pragma unroll
    for (int it = 0; it < 3; ++it) {
        int idx = t + (it << 8);
        if (idx < 672) {
            *(uint4*)&Pl[idx << 3] = make_uint4(0, 0, 0, 0);
            *(uint4*)&Vt[idx << 3] = make_uint4(0, 0, 0, 0);
        }
    }
    __syncthreads();

    if (t < 140) {
        int r = t / 14, c = t % 14;
        uint2 kr = *(const uint2*)&kb[(rs + r) * (WD * LR) + (cs + c) * LR];
        Ksf[t] = make_float4(bf2f(kr.x & 0xffff), bf2f_hi(kr.x),
                             bf2f(kr.y & 0xffff), bf2f_hi(kr.y));
    }
    if (t < 169) Rs[t] = rpb[h * 169 + t];
#pragma unroll
    for (int it = 0; it < 3; ++it) {
        int idx = t + (it << 8);
        if (idx < 560) {
            int oct = idx / 140, pos = idx % 140;
            int r = pos / 14, c = pos % 14;
            union { uint4 u; ushort hh[8]; } vv;
            vv.u = *(const uint4*)&vb[(rs + r) * (WD * HDIM) + (cs + c) * HDIM + oct * 8];
            ushort* cp = &Vt[(oct * 8) * 168 + pos];
#pragma unroll
            for (int e = 0; e < 8; ++e) cp[e * 168] = vv.hh[e];
        }
    }

    const int q  = t >> 3, p = t & 7;
    const int qi = q >> 3, qj = q & 7;
    const int i = i0 + qi, j = j0 + qj;
    uint2 qr2 = *(const uint2*)&Qb[(size_t)b * QK_PER_B + h * (HD_ * WD * LR) + i * (WD * LR) + j * LR];
    __syncthreads();

    const int sh = min(max(i - 3, 0), HD_ - KW);
    const int sw = min(max(j - 3, 0), WD - KW);
    const int oh = sh - rs, ow = sw - cs;
    const int rb0 = (sh - i + 6) * 13 + (sw - j + 6);
    const float scale = 0.17677669529663687f;
    float qx = bf2f(qr2.x & 0xffff) * scale, qy = bf2f_hi(qr2.x) * scale;
    float qz = bf2f(qr2.y & 0xffff) * scale, qw = bf2f_hi(qr2.y) * scale;

    float sum = 0.f;
    if (p < 7) {
        int kpos  = (oh + p) * 14 + ow;
        int rbase = rb0 + p * 13;
        ushort* prow = &Pl[q * 168 + kpos];
#pragma unroll
        for (int kw = 0; kw < 7; ++kw) {
            float4 kf = Ksf[kpos + kw];
            float d = Rs[rbase + kw];
            d = fmaf(qx, kf.x, d);
            d = fmaf(qy, kf.y, d);
            d = fmaf(qz, kf.z, d);
            d = fmaf(qw, kf.w, d);
            float e = __expf(d);
            sum += e;
            prow[kw] = f2bf(e);
        }
    }
    sum += __shfl_xor(sum, 1);
    sum += __shfl_xor(sum, 2);
    sum += __shfl_xor(sum, 4);
    if (p == 0) invS[q] = 1.0f / sum;
    __syncthreads();

    const int lane = t & 63, w = t >> 6;
    const int col = lane & 15, quad = lane >> 4;
    const int wm = w & 1, wn = w >> 1;
    floatx4 acc = {0.f, 0.f, 0.f, 0.f};
    const ushort* arow = &Pl[(wm * 16 + col) * 168];
    const ushort* brow = &Vt[(wn * 16 + col) * 168];
#pragma unroll
    for (int s = 0; s < 5; ++s) {
        int ko = s * 32 + quad * 8;
        short8 a  = *(const short8*)(arow + ko);
        short8 bb = *(const short8*)(brow + ko);
        acc = __builtin_amdgcn_mfma_f32_16x16x32_bf16(a, bb, acc, 0, 0, 0);
    }

#pragma unroll
    for (int rg = 0; rg < 4; ++rg) {
        int qq = wm * 16 + quad * 4 + rg;
        float iv = invS[qq];
        int ii = i0 + (qq >> 3), jj = j0 + (qq & 7);
        Ab[(((b * HD_ + ii) * WD + jj)) * CD + h * HDIM + wn * 16 + col] = f2bf(acc[rg] * iv);
    }
}

// ---------------- MFMA GEMM: output projection, 64x64 tiles -----------------
__global__ __launch_bounds__(256) void mfma_out64(
    const ushort* __restrict__ Ag, const ushort* __restrict__ Bt,
    const float* __restrict__ bp, float* __restrict__ out)
{
    __shared__ ushort As[64 * 64];   // 8 KB
    __shared__ ushort Bs[64 * 64];   // 8 KB
    const int t = threadIdx.x;
    const int m0 = blockIdx.y * 64, n0 = blockIdx.x * 64;
    const int lane = t & 63, w = t >> 6;
    const int lx = lane & 7, ly = lane >> 3;
    const int koff = (lx ^ ly) << 3;
    const int col = lane & 15, quad = lane >> 4;
    const int swz = (col & 7) << 4;
    const int wm = w >> 1, wn = w & 1;
    char* Ac = (char*)As;
    char* Bc = (char*)Bs;
    floatx4 acc[2][2] = {};

    for (int k0 = 0; k0 < 256; k0 += 64) {
        __syncthreads();
#pragma unroll
        for (int l = 0; l < 2; ++l) {
            int c = (w << 1) + l;
            int row = (c << 3) + ly;
            glds16(&Ag[(m0 + row) * 256 + k0 + koff], &As[c << 9]);
            glds16(&Bt[(n0 + row) * 256 + k0 + koff], &Bs[c << 9]);
        }
        __syncthreads();
#pragma unroll
        for (int kk = 0; kk < 2; ++kk) {
            const int kx = ((kk << 6) + (quad << 4)) ^ swz;
            short8 b0 = *(short8*)(Bc + ((wn << 5) + col) * 128 + kx);
            short8 b1 = *(short8*)(Bc + ((wn << 5) + 16 + col) * 128 + kx);
#pragma unroll
            for (int mt = 0; mt < 2; ++mt) {
                short8 a = *(short8*)(Ac + ((wm << 5) + (mt << 4) + col) * 128 + kx);
                acc[mt][0] = __builtin_amdgcn_mfma_f32_16x16x32_bf16(a, b0, acc[mt][0], 0, 0, 0);
                acc[mt][1] = __builtin_amdgcn_mfma_f32_16x16x32_bf16(a, b1, acc[mt][1], 0, 0, 0);
            }
        }
    }

#pragma unroll
    for (int mt = 0; mt < 2; ++mt) {
#pragma unroll
        for (int nt = 0; nt < 2; ++nt) {
            int gn = n0 + (wn << 5) + (nt << 4) + col;
            float bias = bp[gn];
#pragma unroll
            for (int rg = 0; rg < 4; ++rg) {
                int m = m0 + (wm << 5) + (mt << 4) + (quad << 2) + rg;
                out[m * 256 + gn] = acc[mt][nt][rg] + bias;
            }
        }
    }
}

extern "C" void kernel_launch(void* const* d_in, const int* in_sizes, int n_in,
                              void* d_out, int out_size, void* d_ws, size_t ws_size,
                              hipStream_t stream) {
    const float* x   = (const float*)d_in[0];
    const float* Wq  = (const float*)d_in[1];
    const float* bq  = (const float*)d_in[2];
    const float* Wk  = (const float*)d_in[3];
    const float* bk  = (const float*)d_in[4];
    const float* Wv  = (const float*)d_in[5];
    const float* bv  = (const float*)d_in[6];
    const float* rpb = (const float*)d_in[7];
    const float* Wp  = (const float*)d_in[8];
    const float* bp  = (const float*)d_in[9];
    float* out = (float*)d_out;

    // workspace layout — bf16 intermediates; ~21 MB of 256 MiB ws
    ushort* WpkT = (ushort*)d_ws;          // 81920
    ushort* WpT  = WpkT + 81920;           // 65536
    ushort* Ab   = WpT + 65536;            // 3211264
    ushort* Qb   = Ab + 3211264;           // 401408
    ushort* Kb   = Qb + BD * QK_PER_B;     // 401408
    ushort* Vb   = Kb + BD * QK_PER_B;     // 3211264
    ushort* xb   = Vb + BD * V_PER_B;      // 3211264
    float*  pb   = (float*)(xb + 3211264); // 320

    prep_all<<<(549184 + 255) / 256, 256, 0, stream>>>(
        x, Wq, Wk, Wv, bq, bk, bv, Wp, xb, WpkT, WpT, pb);

    mfma_qkv<<<dim3(5, NROWS / 128), 256, 0, stream>>>(xb, WpkT, pb, Qb, Kb, Vb);

    natten_attn4<<<dim3(7, 14, 32), 256, 0, stream>>>(Qb, Kb, Vb, rpb, Ab);

    mfma_out64<<<dim3(4, 196), 256, 0, stream>>>(Ab, WpT, bp, out);
}